// Round 6
// baseline (292.203 us; speedup 1.0000x reference)
//
#include <hip/hip_runtime.h>
#include <hip/hip_bf16.h>
#include <hip/hip_fp16.h>
#include <stdint.h>

#define Bc 4
#define Sc 2048
#define Ec 512
#define Hc 8
#define Dc 64
#define HDc 512

typedef __attribute__((ext_vector_type(8))) short bf16x8;
typedef __attribute__((ext_vector_type(4))) _Float16 f16x4;
typedef __attribute__((ext_vector_type(8))) _Float16 f16x8;
typedef __attribute__((ext_vector_type(4))) float f32x4;
typedef unsigned int u32;

__device__ __forceinline__ unsigned short f2bf(float x) {
    union { float f; unsigned u; } v; v.f = x;
    unsigned r = v.u + 0x7FFFu + ((v.u >> 16) & 1u);
    return (unsigned short)(r >> 16);
}

__device__ __forceinline__ unsigned pkbf2(float a, float b) {
    float2 f; f.x = a; f.y = b;
    __hip_bfloat162 h = __float22bfloat162_rn(f);
    union { __hip_bfloat162 h2; unsigned u; } u; u.h2 = h;
    return u.u;
}

__device__ __forceinline__ unsigned short f2h(float x) {
    return __half_as_ushort(__float2half_rn(x));
}

__device__ __forceinline__ unsigned pkh2(float a, float b) {
    union { __half2 h2; unsigned u; } u;
    u.h2 = __floats2half2_rn(a, b);
    return u.u;
}

__device__ __forceinline__ uint4 pack8(float4 a, float4 b) {
    uint4 v;
    v.x = pkbf2(a.x, a.y); v.y = pkbf2(a.z, a.w);
    v.z = pkbf2(b.x, b.y); v.w = pkbf2(b.z, b.w);
    return v;
}

// async global->LDS, 16B per lane; LDS dest = uniform base + lane*16
__device__ __forceinline__ void gload_lds(const void* g, void* l) {
    __builtin_amdgcn_global_load_lds(
        (const __attribute__((address_space(1))) u32*)g,
        (__attribute__((address_space(3))) u32*)l,
        16, 0, 0);
}

// V token permutation within a 64-token tile: tok = n*16 + qd*4 + r
// -> idx = qd*16 + (n>>1)*8 + (n&1)*4 + r   (so a lane's PV fragment pair
//    {n=2a, n=2a+1} x {r=0..3} for its quad qd is one contiguous 16B run)
__device__ __forceinline__ int vperm(int mt, int c) {
    return ((c >> 2) << 4) + ((mt >> 1) << 3) + ((mt & 1) << 2) + (c & 3);
}

// ---------------------------------------------------------------------------
// Kernel 1: prep. blocks 0..255: weight transpose->bf16 Wt[z][n][k];
// 256..2303: mask bit-pack; 2304..8447: X fp32 -> bf16 (q,k,v).
__global__ __launch_bounds__(256) void prep(
    const int* __restrict__ mask, unsigned long long* __restrict__ bits,
    const float* __restrict__ W0, const float* __restrict__ W1,
    const float* __restrict__ W2, const float* __restrict__ W3,
    unsigned short* __restrict__ Wt,
    const float* __restrict__ Xq, const float* __restrict__ Xk,
    const float* __restrict__ Xv, unsigned short* __restrict__ Xb)
{
    const int blk = blockIdx.x;
    __shared__ float t[64][65];
    if (blk < 256) {
        const int z = blk >> 6;
        const float* W = z == 0 ? W0 : (z == 1 ? W1 : (z == 2 ? W2 : W3));
        unsigned short* O = Wt + (size_t)z * Ec * HDc;
        const int k0 = ((blk >> 3) & 7) * 64, n0 = (blk & 7) * 64;
#pragma unroll
        for (int i = 0; i < 16; i++) {
            int idx = threadIdx.x + 256 * i;
            int kr = idx >> 6, nc = idx & 63;
            t[nc][kr] = W[(size_t)(k0 + kr) * HDc + n0 + nc];
        }
        __syncthreads();
#pragma unroll
        for (int i = 0; i < 16; i++) {
            int idx = threadIdx.x + 256 * i;
            int nr = idx >> 6, kc = idx & 63;
            O[(size_t)(n0 + nr) * Ec + k0 + kc] = f2bf(t[nr][kc]);
        }
    } else if (blk < 2304) {
        const int lane = threadIdx.x & 63;
        int wave = ((blk - 256) * 256 + (int)threadIdx.x) >> 6;
        const int nwaves = (2048 * 256) >> 6;
        const int nwords = (Bc * Sc * Sc) / 64;
        for (int w = wave; w < nwords; w += nwaves) {
            int m = mask[(size_t)w * 64 + lane];
            unsigned long long b = __ballot(m != 0);
            if (lane == 0) bits[w] = b;
        }
    } else {
        const int zi = blk - 2304;
        const int z = zi >> 11, wi = zi & 2047;
        const float* X = z == 0 ? Xq : (z == 1 ? Xk : Xv);
        const size_t off = ((size_t)wi * 256 + threadIdx.x) * 8;
        const float4* p = (const float4*)(X + off);
        float4 f0 = p[0], f1 = p[1];
        *(uint4*)(Xb + (size_t)z * 4194304 + off) = pack8(f0, f1);
    }
}

// ---------------------------------------------------------------------------
// Kernel 2: fused QKV projection, 128x128 tiles, both operands via
// global_load_lds (bf16). grid (4 n, 64 m, 3 z).
// z=0 -> Q (pre-scaled 1/8); z=1 -> K; z=2 -> V fp16, per-head transposed +
// token-permuted: Vt[b][h][d][tile*64 + vperm(tok)].
__global__ __launch_bounds__(256) void proj_gemm(
    const unsigned short* __restrict__ Xb, const unsigned short* __restrict__ Wt,
    const float* __restrict__ bq, const float* __restrict__ bk, const float* __restrict__ bv,
    unsigned short* __restrict__ Oq, unsigned short* __restrict__ Ok,
    unsigned short* __restrict__ Vt)
{
    const int z = blockIdx.z;
    const unsigned short* Xz = Xb + (size_t)z * 4194304;
    const unsigned short* Bt = Wt + (size_t)z * Ec * HDc;
    const float* bias = z == 0 ? bq : (z == 1 ? bk : bv);

    const int n0 = blockIdx.x * 128;
    const int m0 = blockIdx.y * 128;
    const int tid = threadIdx.x, lane = tid & 63, w = tid >> 6;
    const int c = lane & 15, quad = lane >> 4;
    const int wm = w & 1, wn = w >> 1;

    __shared__ unsigned short As[128 * 64];
    __shared__ unsigned short Bs[128 * 64];

    f32x4 acc[4][4];
#pragma unroll
    for (int i = 0; i < 4; i++)
#pragma unroll
        for (int j = 0; j < 4; j++) acc[i][j] = (f32x4){0.f, 0.f, 0.f, 0.f};

    for (int k0 = 0; k0 < Ec; k0 += 64) {
        __syncthreads();
#pragma unroll
        for (int jj = 0; jj < 4; jj++) {
            int rb = w * 32 + jj * 8;
            int row = rb + (lane >> 3);
            int dg = (lane & 7) ^ (row & 7);
            gload_lds(Bt + (size_t)(n0 + row) * Ec + k0 + dg * 8, &Bs[rb * 64]);
            gload_lds(Xz + (size_t)(m0 + row) * Ec + k0 + dg * 8, &As[rb * 64]);
        }
        __syncthreads();
#pragma unroll
        for (int ks = 0; ks < 2; ks++) {
            int kg = ks * 4 + quad;
            bf16x8 af[4], bfr[4];
#pragma unroll
            for (int mt = 0; mt < 4; mt++) {
                int row = wm * 64 + mt * 16 + c;
                af[mt] = *(const bf16x8*)&As[row * 64 + ((kg ^ (row & 7)) * 8)];
            }
#pragma unroll
            for (int nt = 0; nt < 4; nt++) {
                int row = wn * 64 + nt * 16 + c;
                bfr[nt] = *(const bf16x8*)&Bs[row * 64 + ((kg ^ (row & 7)) * 8)];
            }
            if (z < 2) {
#pragma unroll
                for (int mt = 0; mt < 4; mt++)
#pragma unroll
                    for (int nt = 0; nt < 4; nt++)
                        acc[mt][nt] = __builtin_amdgcn_mfma_f32_16x16x32_bf16(af[mt], bfr[nt], acc[mt][nt], 0, 0, 0);
            } else {
#pragma unroll
                for (int mt = 0; mt < 4; mt++)
#pragma unroll
                    for (int nt = 0; nt < 4; nt++)
                        acc[mt][nt] = __builtin_amdgcn_mfma_f32_16x16x32_bf16(bfr[nt], af[mt], acc[mt][nt], 0, 0, 0);
            }
        }
    }

    if (z < 2) {
        unsigned short* O = z == 0 ? Oq : Ok;
        const float qs = z == 0 ? 0.125f : 1.0f;   // fold 1/sqrt(D) into Q (exact)
#pragma unroll
        for (int mt = 0; mt < 4; mt++)
#pragma unroll
            for (int r = 0; r < 4; r++) {
                int gm = m0 + wm * 64 + mt * 16 + quad * 4 + r;
#pragma unroll
                for (int nt = 0; nt < 4; nt++) {
                    int gn = n0 + wn * 64 + nt * 16 + c;
                    O[(size_t)gm * HDc + gn] = f2bf((acc[mt][nt][r] + bias[gn]) * qs);
                }
            }
    } else {
        // transposed + token-permuted V epilogue. acc cols = token (c), rows = d.
#pragma unroll
        for (int mt = 0; mt < 4; mt++) {
            int gm = m0 + wm * 64 + mt * 16 + c;     // token
            int bb = gm >> 11, sPos = gm & (Sc - 1);
            int tbase = (sPos & ~63) + vperm(mt, c); // tok = mt*16+c within tile
#pragma unroll
            for (int nt = 0; nt < 4; nt++)
#pragma unroll
                for (int r = 0; r < 4; r++) {
                    int ng = n0 + wn * 64 + nt * 16 + quad * 4 + r;
                    int hh = ng >> 6, d = ng & 63;
                    Vt[((size_t)(bb * Hc + hh) * Dc + d) * Sc + tbase] = f2h(acc[mt][nt][r] + bias[ng]);
                }
        }
    }
}

// ---------------------------------------------------------------------------
// Kernel 3: flash attention, S^T form, 32 q per wave (dual fragments),
// 2-wave (128-thread) blocks, double-buffered async K/V staging, V reads as
// conflict-free ds_read_b128 via token permutation. P in registers (fp16).
__global__ __launch_bounds__(128, 2) void attn_kernel(
    const unsigned short* __restrict__ Qb, const unsigned short* __restrict__ Kb,
    const unsigned short* __restrict__ Vt, const unsigned long long* __restrict__ Mb,
    unsigned short* __restrict__ Ob)
{
    const int qt = blockIdx.x;   // 0..31 (64 q per block)
    const int h  = blockIdx.y;
    const int b  = blockIdx.z;
    const int q0 = qt * 64;
    const int tid = threadIdx.x, lane = tid & 63, w = tid >> 6;  // w in {0,1}
    const int c = lane & 15, quad = lane >> 4;

    __shared__ unsigned short Ks[2][64 * 64];
    __shared__ unsigned short Vs[2][64 * 64];

    const int q_g0 = q0 + w * 32 + c;
    const int q_g1 = q_g0 + 16;
    const size_t qoff0 = ((size_t)b * Sc + q_g0) * HDc + h * Dc;
    const size_t qoff1 = ((size_t)b * Sc + q_g1) * HDc + h * Dc;

    bf16x8 qf0[2], qf1[2];
#pragma unroll
    for (int ks = 0; ks < 2; ks++) {
        qf0[ks] = *(const bf16x8*)(Qb + qoff0 + ks * 32 + quad * 8);
        qf1[ks] = *(const bf16x8*)(Qb + qoff1 + ks * 32 + quad * 8);
    }

    const unsigned long long* mr0 = Mb + ((size_t)b * Sc + q_g0) * (Sc / 64);
    const unsigned long long* mr1 = Mb + ((size_t)b * Sc + q_g1) * (Sc / 64);
    const size_t kbase = ((size_t)b * Sc) * HDc + h * Dc;
    const size_t vbase = ((size_t)(b * Hc + h)) * Dc * Sc;

    f32x4 o0[4], o1[4], osum0, osum1;
#pragma unroll
    for (int i = 0; i < 4; i++) { o0[i] = (f32x4){0.f,0.f,0.f,0.f}; o1[i] = (f32x4){0.f,0.f,0.f,0.f}; }
    osum0 = (f32x4){0.f, 0.f, 0.f, 0.f};
    osum1 = (f32x4){0.f, 0.f, 0.f, 0.f};

    const f16x4 ones = {(_Float16)1.0f, (_Float16)1.0f, (_Float16)1.0f, (_Float16)1.0f};

    // wave w stages rows w*32..w*32+31 of the 64-row K and V tiles
    auto stage = [&](int kt, int buf) {
#pragma unroll
        for (int j = 0; j < 4; j++) {
            int rb = w * 32 + j * 8;
            int row = rb + (lane >> 3);
            int dg = (lane & 7) ^ (row & 7);
            gload_lds(Kb + kbase + (size_t)(kt * 64 + row) * HDc + dg * 8, &Ks[buf][rb * 64]);
            gload_lds(Vt + vbase + (size_t)row * Sc + kt * 64 + dg * 8, &Vs[buf][rb * 64]);
        }
    };

    stage(0, 0);
    for (int kt = 0; kt < Sc / 64; kt++) {
        const int cur = kt & 1;
        unsigned long long mw0 = mr0[kt];
        unsigned long long mw1 = mr1[kt];
        __syncthreads();                 // drains async loads -> buf cur ready
        if (kt + 1 < Sc / 64) stage(kt + 1, cur ^ 1);

        // S^T tile: D[tok][q] = K . Q^T  (Q pre-scaled by 1/8)
        f32x4 s0[4], s1[4];
#pragma unroll
        for (int nt = 0; nt < 4; nt++) { s0[nt] = (f32x4){0.f,0.f,0.f,0.f}; s1[nt] = (f32x4){0.f,0.f,0.f,0.f}; }
#pragma unroll
        for (int ks = 0; ks < 2; ks++) {
            int kg = ks * 4 + quad;
#pragma unroll
            for (int nt = 0; nt < 4; nt++) {
                int t = nt * 16 + c;
                bf16x8 a = *(const bf16x8*)&Ks[cur][t * 64 + ((kg ^ (t & 7)) * 8)];
                s0[nt] = __builtin_amdgcn_mfma_f32_16x16x32_bf16(a, qf0[ks], s0[nt], 0, 0, 0);
                s1[nt] = __builtin_amdgcn_mfma_f32_16x16x32_bf16(a, qf1[ks], s1[nt], 0, 0, 0);
            }
        }

        // per-lane softmax numerators -> fp16 B-fragments (no LDS, no shuffles)
        u32 mlo0 = (u32)(mw0) >> (quad * 4), mhi0 = (u32)(mw0 >> 32) >> (quad * 4);
        u32 mlo1 = (u32)(mw1) >> (quad * 4), mhi1 = (u32)(mw1 >> 32) >> (quad * 4);
        f16x4 pb0[4], pb1[4];
#pragma unroll
        for (int nt = 0; nt < 4; nt++) {
            u32 ms0 = (nt < 2) ? mlo0 : mhi0;
            u32 ms1 = (nt < 2) ? mlo1 : mhi1;
            float p0[4], p1[4];
#pragma unroll
            for (int r = 0; r < 4; r++) {
                const int sh = (nt & 1) * 16 + r;
                int k0 = ((int)(ms0 << (31 - sh))) >> 31;   // -1 if unmasked
                int k1 = ((int)(ms1 << (31 - sh))) >> 31;
                p0[r] = __int_as_float(__float_as_int(__expf(s0[nt][r])) & k0);
                p1[r] = __int_as_float(__float_as_int(__expf(s1[nt][r])) & k1);
            }
            union { unsigned u[2]; f16x4 v; } pk;
            pk.u[0] = pkh2(p0[0], p0[1]); pk.u[1] = pkh2(p0[2], p0[3]);
            pb0[nt] = pk.v;
            pk.u[0] = pkh2(p1[0], p1[1]); pk.u[1] = pkh2(p1[2], p1[3]);
            pb1[nt] = pk.v;
        }

        // O^T += V^T . P via 16x16x16 fp16 MFMA. V fragment pair (toks for
        // MFMA n=2a and n=2a+1) is one b128 read thanks to the permutation.
#pragma unroll
        for (int a = 0; a < 2; a++) {
#pragma unroll
            for (int dt = 0; dt < 4; dt++) {
                int d = dt * 16 + c;
                union { f16x8 v8; f16x4 v4[2]; } vv;
                vv.v8 = *(const f16x8*)&Vs[cur][d * 64 + (((quad * 2 + a) ^ (d & 7)) * 8)];
                o0[dt] = __builtin_amdgcn_mfma_f32_16x16x16f16(vv.v4[0], pb0[2*a],   o0[dt], 0, 0, 0);
                o0[dt] = __builtin_amdgcn_mfma_f32_16x16x16f16(vv.v4[1], pb0[2*a+1], o0[dt], 0, 0, 0);
                o1[dt] = __builtin_amdgcn_mfma_f32_16x16x16f16(vv.v4[0], pb1[2*a],   o1[dt], 0, 0, 0);
                o1[dt] = __builtin_amdgcn_mfma_f32_16x16x16f16(vv.v4[1], pb1[2*a+1], o1[dt], 0, 0, 0);
            }
            osum0 = __builtin_amdgcn_mfma_f32_16x16x16f16(ones, pb0[2*a],   osum0, 0, 0, 0);
            osum0 = __builtin_amdgcn_mfma_f32_16x16x16f16(ones, pb0[2*a+1], osum0, 0, 0, 0);
            osum1 = __builtin_amdgcn_mfma_f32_16x16x16f16(ones, pb1[2*a],   osum1, 0, 0, 0);
            osum1 = __builtin_amdgcn_mfma_f32_16x16x16f16(ones, pb1[2*a+1], osum1, 0, 0, 0);
        }
    }

    const float inv0 = 1.0f / osum0[0];
    const float inv1 = 1.0f / osum1[0];

#pragma unroll
    for (int dt = 0; dt < 4; dt++) {
        uint2 pk;
        pk.x = pkbf2(o0[dt][0] * inv0, o0[dt][1] * inv0);
        pk.y = pkbf2(o0[dt][2] * inv0, o0[dt][3] * inv0);
        *(uint2*)(Ob + qoff0 + dt * 16 + quad * 4) = pk;
        pk.x = pkbf2(o1[dt][0] * inv1, o1[dt][1] * inv1);
        pk.y = pkbf2(o1[dt][2] * inv1, o1[dt][3] * inv1);
        *(uint2*)(Ob + qoff1 + dt * 16 + quad * 4) = pk;
    }
}

// ---------------------------------------------------------------------------
// Kernel 4: output projection, 64x128 tiles. grid (4 n-blocks, 128 m-blocks).
__global__ __launch_bounds__(256) void out_gemm(
    const unsigned short* __restrict__ Ab, const unsigned short* __restrict__ Bt,
    const float* __restrict__ bias, float* __restrict__ Out)
{
    const int n0 = blockIdx.x * 128;
    const int m0 = blockIdx.y * 64;
    const int tid = threadIdx.x, lane = tid & 63, w = tid >> 6;
    const int c = lane & 15, quad = lane >> 4;
    const int wm = w & 1, wn = w >> 1;

    __shared__ unsigned short As[64 * 64];
    __shared__ unsigned short Bs[128 * 64];

    f32x4 acc[2][4];
#pragma unroll
    for (int i = 0; i < 2; i++)
#pragma unroll
        for (int j = 0; j < 4; j++) acc[i][j] = (f32x4){0.f, 0.f, 0.f, 0.f};

    for (int k0 = 0; k0 < HDc; k0 += 64) {
        __syncthreads();
#pragma unroll
        for (int jj = 0; jj < 4; jj++) {
            int rb = w * 32 + jj * 8;
            int row = rb + (lane >> 3);
            int dg = (lane & 7) ^ (row & 7);
            gload_lds(Bt + (size_t)(n0 + row) * Ec + k0 + dg * 8, &Bs[rb * 64]);
        }
#pragma unroll
        for (int jj = 0; jj < 2; jj++) {
            int rb = w * 16 + jj * 8;
            int row = rb + (lane >> 3);
            int dg = (lane & 7) ^ (row & 7);
            gload_lds(Ab + (size_t)(m0 + row) * HDc + k0 + dg * 8, &As[rb * 64]);
        }
        __syncthreads();
#pragma unroll
        for (int ks = 0; ks < 2; ks++) {
            int kg = ks * 4 + quad;
            bf16x8 af[2], bfr[4];
#pragma unroll
            for (int mt = 0; mt < 2; mt++) {
                int row = wm * 32 + mt * 16 + c;
                af[mt] = *(const bf16x8*)&As[row * 64 + ((kg ^ (row & 7)) * 8)];
            }
#pragma unroll
            for (int nt = 0; nt < 4; nt++) {
                int row = wn * 64 + nt * 16 + c;
                bfr[nt] = *(const bf16x8*)&Bs[row * 64 + ((kg ^ (row & 7)) * 8)];
            }
#pragma unroll
            for (int mt = 0; mt < 2; mt++)
#pragma unroll
                for (int nt = 0; nt < 4; nt++)
                    acc[mt][nt] = __builtin_amdgcn_mfma_f32_16x16x32_bf16(af[mt], bfr[nt], acc[mt][nt], 0, 0, 0);
        }
    }
#pragma unroll
    for (int mt = 0; mt < 2; mt++)
#pragma unroll
        for (int r = 0; r < 4; r++) {
            int gm = m0 + wm * 32 + mt * 16 + quad * 4 + r;
#pragma unroll
            for (int nt = 0; nt < 4; nt++) {
                int gn = n0 + wn * 64 + nt * 16 + c;
                Out[(size_t)gm * Ec + gn] = acc[mt][nt][r] + bias[gn];
            }
        }
}

// ---------------------------------------------------------------------------
extern "C" void kernel_launch(void* const* d_in, const int* in_sizes, int n_in,
                              void* d_out, int out_size, void* d_ws, size_t ws_size,
                              hipStream_t stream)
{
    const float* xq = (const float*)d_in[0];
    const float* xk = (const float*)d_in[1];
    const float* xv = (const float*)d_in[2];
    const int* mask = (const int*)d_in[3];
    const float* wq = (const float*)d_in[4];
    const float* bq = (const float*)d_in[5];
    const float* wk = (const float*)d_in[6];
    const float* bk = (const float*)d_in[7];
    const float* wv = (const float*)d_in[8];
    const float* bv = (const float*)d_in[9];
    const float* wo = (const float*)d_in[10];
    const float* bo = (const float*)d_in[11];
    float* out = (float*)d_out;

    char* ws = (char*)d_ws;
    const size_t MB = 1024 * 1024;
    unsigned short* qb = (unsigned short*)(ws + 0 * MB);    // 8 MB
    unsigned short* kb = (unsigned short*)(ws + 8 * MB);    // 8 MB
    unsigned short* vt = (unsigned short*)(ws + 16 * MB);   // 8 MB
    unsigned short* xb = (unsigned short*)(ws + 24 * MB);   // 24 MB (dead after proj)
    unsigned short* ab = (unsigned short*)(ws + 24 * MB);   // 8 MB (reuses xb space)
    unsigned long long* mb = (unsigned long long*)(ws + 48 * MB); // 2 MB
    unsigned short* wt = (unsigned short*)(ws + 50 * MB);   // 2 MB

    hipLaunchKernelGGL(prep, dim3(8448), dim3(256), 0, stream,
                       mask, mb, wq, wk, wv, wo, wt, xq, xk, xv, xb);

    hipLaunchKernelGGL(proj_gemm, dim3(4, 64, 3), dim3(256), 0, stream,
                       xb, wt, bq, bk, bv, qb, kb, vt);

    hipLaunchKernelGGL(attn_kernel, dim3(32, 8, 4), dim3(128), 0, stream,
                       qb, kb, vt, mb, ab);

    hipLaunchKernelGGL(out_gemm, dim3(4, 128), dim3(256), 0, stream,
                       ab, wt + 3 * (size_t)Ec * HDc, bo, out);
}

// Round 7
// 270.680 us; speedup vs baseline: 1.0795x; 1.0795x over previous
//
#include <hip/hip_runtime.h>
#include <hip/hip_bf16.h>
#include <hip/hip_fp16.h>
#include <stdint.h>

#define Bc 4
#define Sc 2048
#define Ec 512
#define Hc 8
#define Dc 64
#define HDc 512

typedef __attribute__((ext_vector_type(8))) short bf16x8;
typedef __attribute__((ext_vector_type(4))) _Float16 f16x4;
typedef __attribute__((ext_vector_type(8))) _Float16 f16x8;
typedef __attribute__((ext_vector_type(4))) float f32x4;
typedef unsigned int u32;

__device__ __forceinline__ unsigned short f2bf(float x) {
    union { float f; unsigned u; } v; v.f = x;
    unsigned r = v.u + 0x7FFFu + ((v.u >> 16) & 1u);
    return (unsigned short)(r >> 16);
}

__device__ __forceinline__ unsigned pkbf2(float a, float b) {
    float2 f; f.x = a; f.y = b;
    __hip_bfloat162 h = __float22bfloat162_rn(f);
    union { __hip_bfloat162 h2; unsigned u; } u; u.h2 = h;
    return u.u;
}

__device__ __forceinline__ unsigned short f2h(float x) {
    return __half_as_ushort(__float2half_rn(x));
}

__device__ __forceinline__ unsigned pkh2(float a, float b) {
    union { __half2 h2; unsigned u; } u;
    u.h2 = __floats2half2_rn(a, b);
    return u.u;
}

__device__ __forceinline__ uint4 pack8(float4 a, float4 b) {
    uint4 v;
    v.x = pkbf2(a.x, a.y); v.y = pkbf2(a.z, a.w);
    v.z = pkbf2(b.x, b.y); v.w = pkbf2(b.z, b.w);
    return v;
}

// async global->LDS, 16B per lane; LDS dest = uniform base + lane*16
__device__ __forceinline__ void gload_lds(const void* g, void* l) {
    __builtin_amdgcn_global_load_lds(
        (const __attribute__((address_space(1))) u32*)g,
        (__attribute__((address_space(3))) u32*)l,
        16, 0, 0);
}

// V token permutation within a 64-token tile: tok = n*16 + qd*4 + r
// -> idx = qd*16 + (n>>1)*8 + (n&1)*4 + r   (a lane's PV fragment pair
//    {n=2a, n=2a+1} x {r=0..3} for its quad qd is one contiguous 16B run)
__device__ __forceinline__ int vperm(int mt, int c) {
    return ((c >> 2) << 4) + ((mt >> 1) << 3) + ((mt & 1) << 2) + (c & 3);
}

// ---------------------------------------------------------------------------
// Kernel 1: prep. blocks 0..255: weight transpose->bf16 Wt[z][n][k];
// 256..2303: mask bit-pack; 2304..8447: X fp32 -> bf16 (q,k,v).
__global__ __launch_bounds__(256) void prep(
    const int* __restrict__ mask, unsigned long long* __restrict__ bits,
    const float* __restrict__ W0, const float* __restrict__ W1,
    const float* __restrict__ W2, const float* __restrict__ W3,
    unsigned short* __restrict__ Wt,
    const float* __restrict__ Xq, const float* __restrict__ Xk,
    const float* __restrict__ Xv, unsigned short* __restrict__ Xb)
{
    const int blk = blockIdx.x;
    __shared__ float t[64][65];
    if (blk < 256) {
        const int z = blk >> 6;
        const float* W = z == 0 ? W0 : (z == 1 ? W1 : (z == 2 ? W2 : W3));
        unsigned short* O = Wt + (size_t)z * Ec * HDc;
        const int k0 = ((blk >> 3) & 7) * 64, n0 = (blk & 7) * 64;
#pragma unroll
        for (int i = 0; i < 16; i++) {
            int idx = threadIdx.x + 256 * i;
            int kr = idx >> 6, nc = idx & 63;
            t[nc][kr] = W[(size_t)(k0 + kr) * HDc + n0 + nc];
        }
        __syncthreads();
#pragma unroll
        for (int i = 0; i < 16; i++) {
            int idx = threadIdx.x + 256 * i;
            int nr = idx >> 6, kc = idx & 63;
            O[(size_t)(n0 + nr) * Ec + k0 + kc] = f2bf(t[nr][kc]);
        }
    } else if (blk < 2304) {
        const int lane = threadIdx.x & 63;
        int wave = ((blk - 256) * 256 + (int)threadIdx.x) >> 6;
        const int nwaves = (2048 * 256) >> 6;
        const int nwords = (Bc * Sc * Sc) / 64;
        for (int w = wave; w < nwords; w += nwaves) {
            int m = mask[(size_t)w * 64 + lane];
            unsigned long long b = __ballot(m != 0);
            if (lane == 0) bits[w] = b;
        }
    } else {
        const int zi = blk - 2304;
        const int z = zi >> 11, wi = zi & 2047;
        const float* X = z == 0 ? Xq : (z == 1 ? Xk : Xv);
        const size_t off = ((size_t)wi * 256 + threadIdx.x) * 8;
        const float4* p = (const float4*)(X + off);
        float4 f0 = p[0], f1 = p[1];
        *(uint4*)(Xb + (size_t)z * 4194304 + off) = pack8(f0, f1);
    }
}

// ---------------------------------------------------------------------------
// Kernel 2: fused QKV projection, 128x128 tiles, both operands via
// global_load_lds (bf16). grid (4 n, 64 m, 3 z).
// z=0 -> Q (pre-scaled 1/8); z=1 -> K; z=2 -> V fp16, per-head transposed +
// token-permuted: Vt[b][h][d][tile*64 + vperm(tok)].
__global__ __launch_bounds__(256) void proj_gemm(
    const unsigned short* __restrict__ Xb, const unsigned short* __restrict__ Wt,
    const float* __restrict__ bq, const float* __restrict__ bk, const float* __restrict__ bv,
    unsigned short* __restrict__ Oq, unsigned short* __restrict__ Ok,
    unsigned short* __restrict__ Vt)
{
    const int z = blockIdx.z;
    const unsigned short* Xz = Xb + (size_t)z * 4194304;
    const unsigned short* Bt = Wt + (size_t)z * Ec * HDc;
    const float* bias = z == 0 ? bq : (z == 1 ? bk : bv);

    const int n0 = blockIdx.x * 128;
    const int m0 = blockIdx.y * 128;
    const int tid = threadIdx.x, lane = tid & 63, w = tid >> 6;
    const int c = lane & 15, quad = lane >> 4;
    const int wm = w & 1, wn = w >> 1;

    __shared__ unsigned short As[128 * 64];
    __shared__ unsigned short Bs[128 * 64];

    f32x4 acc[4][4];
#pragma unroll
    for (int i = 0; i < 4; i++)
#pragma unroll
        for (int j = 0; j < 4; j++) acc[i][j] = (f32x4){0.f, 0.f, 0.f, 0.f};

    for (int k0 = 0; k0 < Ec; k0 += 64) {
        __syncthreads();
#pragma unroll
        for (int jj = 0; jj < 4; jj++) {
            int rb = w * 32 + jj * 8;
            int row = rb + (lane >> 3);
            int dg = (lane & 7) ^ (row & 7);
            gload_lds(Bt + (size_t)(n0 + row) * Ec + k0 + dg * 8, &Bs[rb * 64]);
            gload_lds(Xz + (size_t)(m0 + row) * Ec + k0 + dg * 8, &As[rb * 64]);
        }
        __syncthreads();
#pragma unroll
        for (int ks = 0; ks < 2; ks++) {
            int kg = ks * 4 + quad;
            bf16x8 af[4], bfr[4];
#pragma unroll
            for (int mt = 0; mt < 4; mt++) {
                int row = wm * 64 + mt * 16 + c;
                af[mt] = *(const bf16x8*)&As[row * 64 + ((kg ^ (row & 7)) * 8)];
            }
#pragma unroll
            for (int nt = 0; nt < 4; nt++) {
                int row = wn * 64 + nt * 16 + c;
                bfr[nt] = *(const bf16x8*)&Bs[row * 64 + ((kg ^ (row & 7)) * 8)];
            }
            if (z < 2) {
#pragma unroll
                for (int mt = 0; mt < 4; mt++)
#pragma unroll
                    for (int nt = 0; nt < 4; nt++)
                        acc[mt][nt] = __builtin_amdgcn_mfma_f32_16x16x32_bf16(af[mt], bfr[nt], acc[mt][nt], 0, 0, 0);
            } else {
#pragma unroll
                for (int mt = 0; mt < 4; mt++)
#pragma unroll
                    for (int nt = 0; nt < 4; nt++)
                        acc[mt][nt] = __builtin_amdgcn_mfma_f32_16x16x32_bf16(bfr[nt], af[mt], acc[mt][nt], 0, 0, 0);
            }
        }
    }

    if (z < 2) {
        unsigned short* O = z == 0 ? Oq : Ok;
        const float qs = z == 0 ? 0.125f : 1.0f;   // fold 1/sqrt(D) into Q (exact)
#pragma unroll
        for (int mt = 0; mt < 4; mt++)
#pragma unroll
            for (int r = 0; r < 4; r++) {
                int gm = m0 + wm * 64 + mt * 16 + quad * 4 + r;
#pragma unroll
                for (int nt = 0; nt < 4; nt++) {
                    int gn = n0 + wn * 64 + nt * 16 + c;
                    O[(size_t)gm * HDc + gn] = f2bf((acc[mt][nt][r] + bias[gn]) * qs);
                }
            }
    } else {
        // transposed + token-permuted V epilogue. acc cols = token (c), rows = d.
#pragma unroll
        for (int mt = 0; mt < 4; mt++) {
            int gm = m0 + wm * 64 + mt * 16 + c;     // token
            int bb = gm >> 11, sPos = gm & (Sc - 1);
            int tbase = (sPos & ~63) + vperm(mt, c); // tok = mt*16+c within tile
#pragma unroll
            for (int nt = 0; nt < 4; nt++)
#pragma unroll
                for (int r = 0; r < 4; r++) {
                    int ng = n0 + wn * 64 + nt * 16 + quad * 4 + r;
                    int hh = ng >> 6, d = ng & 63;
                    Vt[((size_t)(bb * Hc + hh) * Dc + d) * Sc + tbase] = f2h(acc[mt][nt][r] + bias[ng]);
                }
        }
    }
}

// ---------------------------------------------------------------------------
// Kernel 3: flash attention, S^T form. R5 occupancy structure (4-wave blocks,
// 16 q/wave, 4 blocks/CU) + R6 permuted-V conflict-free b128 PV reads.
// P stays in registers (fp16); lsum via ones-row MFMA.
__global__ __launch_bounds__(256, 4) void attn_kernel(
    const unsigned short* __restrict__ Qb, const unsigned short* __restrict__ Kb,
    const unsigned short* __restrict__ Vt, const unsigned long long* __restrict__ Mb,
    unsigned short* __restrict__ Ob)
{
    const int qt = blockIdx.x;   // 0..31
    const int h  = blockIdx.y;
    const int b  = blockIdx.z;
    const int q0 = qt * 64;
    const int tid = threadIdx.x, lane = tid & 63, w = tid >> 6;
    const int c = lane & 15, quad = lane >> 4;

    __shared__ unsigned short Ks[2][64 * 64];
    __shared__ unsigned short Vs[2][64 * 64];

    const int qg = q0 + w * 16 + c;
    const size_t qoff = ((size_t)b * Sc + qg) * HDc + h * Dc;

    bf16x8 qf[2];
    qf[0] = *(const bf16x8*)(Qb + qoff + quad * 8);
    qf[1] = *(const bf16x8*)(Qb + qoff + 32 + quad * 8);

    const unsigned long long* mr = Mb + ((size_t)b * Sc + qg) * (Sc / 64);
    const size_t kbase = ((size_t)b * Sc) * HDc + h * Dc;
    const size_t vbase = ((size_t)(b * Hc + h)) * Dc * Sc;

    f32x4 o[4], osum;
#pragma unroll
    for (int i = 0; i < 4; i++) o[i] = (f32x4){0.f, 0.f, 0.f, 0.f};
    osum = (f32x4){0.f, 0.f, 0.f, 0.f};

    const f16x4 ones = {(_Float16)1.0f, (_Float16)1.0f, (_Float16)1.0f, (_Float16)1.0f};

    auto stage = [&](int kt, int buf) {
#pragma unroll
        for (int j = 0; j < 2; j++) {
            int rb = w * 16 + j * 8;
            int row = rb + (lane >> 3);
            int dg = (lane & 7) ^ (row & 7);
            gload_lds(Kb + kbase + (size_t)(kt * 64 + row) * HDc + dg * 8, &Ks[buf][rb * 64]);
            gload_lds(Vt + vbase + (size_t)row * Sc + kt * 64 + dg * 8, &Vs[buf][rb * 64]);
        }
    };

    stage(0, 0);
    for (int kt = 0; kt < Sc / 64; kt++) {
        const int cur = kt & 1;
        unsigned long long mw = mr[kt];
        __syncthreads();                 // drains async loads -> buf cur ready
        if (kt + 1 < Sc / 64) stage(kt + 1, cur ^ 1);

        // S^T tile: D[tok][q] = K . Q^T  (Q pre-scaled by 1/8)
        f32x4 s[4];
#pragma unroll
        for (int nt = 0; nt < 4; nt++) s[nt] = (f32x4){0.f, 0.f, 0.f, 0.f};
#pragma unroll
        for (int ks = 0; ks < 2; ks++) {
            int kg = ks * 4 + quad;
#pragma unroll
            for (int nt = 0; nt < 4; nt++) {
                int t = nt * 16 + c;
                bf16x8 a = *(const bf16x8*)&Ks[cur][t * 64 + ((kg ^ (t & 7)) * 8)];
                s[nt] = __builtin_amdgcn_mfma_f32_16x16x32_bf16(a, qf[ks], s[nt], 0, 0, 0);
            }
        }

        // per-lane softmax numerators -> fp16 B-fragments (no LDS, no shuffles)
        u32 mlo = (u32)(mw) >> (quad * 4);          // bit (nt*16+r) for nt=0,1
        u32 mhi = (u32)(mw >> 32) >> (quad * 4);    // for nt=2,3
        f16x4 pb[4];
#pragma unroll
        for (int nt = 0; nt < 4; nt++) {
            u32 msrc = (nt < 2) ? mlo : mhi;
            float p[4];
#pragma unroll
            for (int r = 0; r < 4; r++) {
                const int sh = (nt & 1) * 16 + r;
                int keep = ((int)(msrc << (31 - sh))) >> 31;   // -1 if unmasked
                float e = __expf(s[nt][r]);
                p[r] = __int_as_float(__float_as_int(e) & keep);
            }
            union { unsigned u[2]; f16x4 v; } pk;
            pk.u[0] = pkh2(p[0], p[1]);
            pk.u[1] = pkh2(p[2], p[3]);
            pb[nt] = pk.v;
        }

        // O^T += V^T . P via 16x16x16 fp16 MFMA. V fragment pair (MFMA n=2a,
        // 2a+1) is one conflict-free b128 read thanks to the token permutation.
#pragma unroll
        for (int a = 0; a < 2; a++) {
#pragma unroll
            for (int dt = 0; dt < 4; dt++) {
                int d = dt * 16 + c;
                union { f16x8 v8; f16x4 v4[2]; } vv;
                vv.v8 = *(const f16x8*)&Vs[cur][d * 64 + (((quad * 2 + a) ^ (d & 7)) * 8)];
                o[dt] = __builtin_amdgcn_mfma_f32_16x16x16f16(vv.v4[0], pb[2*a],   o[dt], 0, 0, 0);
                o[dt] = __builtin_amdgcn_mfma_f32_16x16x16f16(vv.v4[1], pb[2*a+1], o[dt], 0, 0, 0);
            }
            osum = __builtin_amdgcn_mfma_f32_16x16x16f16(ones, pb[2*a],   osum, 0, 0, 0);
            osum = __builtin_amdgcn_mfma_f32_16x16x16f16(ones, pb[2*a+1], osum, 0, 0, 0);
        }
    }

    const float inv = 1.0f / osum[0];   // full row sum for this lane's q

#pragma unroll
    for (int dt = 0; dt < 4; dt++) {
        uint2 pk;
        pk.x = pkbf2(o[dt][0] * inv, o[dt][1] * inv);
        pk.y = pkbf2(o[dt][2] * inv, o[dt][3] * inv);
        *(uint2*)(Ob + qoff + dt * 16 + quad * 4) = pk;
    }
}

// ---------------------------------------------------------------------------
// Kernel 4: output projection, 64x128 tiles. grid (4 n-blocks, 128 m-blocks).
__global__ __launch_bounds__(256) void out_gemm(
    const unsigned short* __restrict__ Ab, const unsigned short* __restrict__ Bt,
    const float* __restrict__ bias, float* __restrict__ Out)
{
    const int n0 = blockIdx.x * 128;
    const int m0 = blockIdx.y * 64;
    const int tid = threadIdx.x, lane = tid & 63, w = tid >> 6;
    const int c = lane & 15, quad = lane >> 4;
    const int wm = w & 1, wn = w >> 1;

    __shared__ unsigned short As[64 * 64];
    __shared__ unsigned short Bs[128 * 64];

    f32x4 acc[2][4];
#pragma unroll
    for (int i = 0; i < 2; i++)
#pragma unroll
        for (int j = 0; j < 4; j++) acc[i][j] = (f32x4){0.f, 0.f, 0.f, 0.f};

    for (int k0 = 0; k0 < HDc; k0 += 64) {
        __syncthreads();
#pragma unroll
        for (int jj = 0; jj < 4; jj++) {
            int rb = w * 32 + jj * 8;
            int row = rb + (lane >> 3);
            int dg = (lane & 7) ^ (row & 7);
            gload_lds(Bt + (size_t)(n0 + row) * Ec + k0 + dg * 8, &Bs[rb * 64]);
        }
#pragma unroll
        for (int jj = 0; jj < 2; jj++) {
            int rb = w * 16 + jj * 8;
            int row = rb + (lane >> 3);
            int dg = (lane & 7) ^ (row & 7);
            gload_lds(Ab + (size_t)(m0 + row) * HDc + k0 + dg * 8, &As[rb * 64]);
        }
        __syncthreads();
#pragma unroll
        for (int ks = 0; ks < 2; ks++) {
            int kg = ks * 4 + quad;
            bf16x8 af[2], bfr[4];
#pragma unroll
            for (int mt = 0; mt < 2; mt++) {
                int row = wm * 32 + mt * 16 + c;
                af[mt] = *(const bf16x8*)&As[row * 64 + ((kg ^ (row & 7)) * 8)];
            }
#pragma unroll
            for (int nt = 0; nt < 4; nt++) {
                int row = wn * 64 + nt * 16 + c;
                bfr[nt] = *(const bf16x8*)&Bs[row * 64 + ((kg ^ (row & 7)) * 8)];
            }
#pragma unroll
            for (int mt = 0; mt < 2; mt++)
#pragma unroll
                for (int nt = 0; nt < 4; nt++)
                    acc[mt][nt] = __builtin_amdgcn_mfma_f32_16x16x32_bf16(af[mt], bfr[nt], acc[mt][nt], 0, 0, 0);
        }
    }
#pragma unroll
    for (int mt = 0; mt < 2; mt++)
#pragma unroll
        for (int r = 0; r < 4; r++) {
            int gm = m0 + wm * 32 + mt * 16 + quad * 4 + r;
#pragma unroll
            for (int nt = 0; nt < 4; nt++) {
                int gn = n0 + wn * 64 + nt * 16 + c;
                Out[(size_t)gm * Ec + gn] = acc[mt][nt][r] + bias[gn];
            }
        }
}

// ---------------------------------------------------------------------------
extern "C" void kernel_launch(void* const* d_in, const int* in_sizes, int n_in,
                              void* d_out, int out_size, void* d_ws, size_t ws_size,
                              hipStream_t stream)
{
    const float* xq = (const float*)d_in[0];
    const float* xk = (const float*)d_in[1];
    const float* xv = (const float*)d_in[2];
    const int* mask = (const int*)d_in[3];
    const float* wq = (const float*)d_in[4];
    const float* bq = (const float*)d_in[5];
    const float* wk = (const float*)d_in[6];
    const float* bk = (const float*)d_in[7];
    const float* wv = (const float*)d_in[8];
    const float* bv = (const float*)d_in[9];
    const float* wo = (const float*)d_in[10];
    const float* bo = (const float*)d_in[11];
    float* out = (float*)d_out;

    char* ws = (char*)d_ws;
    const size_t MB = 1024 * 1024;
    unsigned short* qb = (unsigned short*)(ws + 0 * MB);    // 8 MB
    unsigned short* kb = (unsigned short*)(ws + 8 * MB);    // 8 MB
    unsigned short* vt = (unsigned short*)(ws + 16 * MB);   // 8 MB
    unsigned short* xb = (unsigned short*)(ws + 24 * MB);   // 24 MB (dead after proj)
    unsigned short* ab = (unsigned short*)(ws + 24 * MB);   // 8 MB (reuses xb space)
    unsigned long long* mb = (unsigned long long*)(ws + 48 * MB); // 2 MB
    unsigned short* wt = (unsigned short*)(ws + 50 * MB);   // 2 MB

    hipLaunchKernelGGL(prep, dim3(8448), dim3(256), 0, stream,
                       mask, mb, wq, wk, wv, wo, wt, xq, xk, xv, xb);

    hipLaunchKernelGGL(proj_gemm, dim3(4, 64, 3), dim3(256), 0, stream,
                       xb, wt, bq, bk, bv, qb, kb, vt);

    hipLaunchKernelGGL(attn_kernel, dim3(32, 8, 4), dim3(256), 0, stream,
                       qb, kb, vt, mb, ab);

    hipLaunchKernelGGL(out_gemm, dim3(4, 128), dim3(256), 0, stream,
                       ab, wt + 3 * (size_t)Ec * HDc, bo, out);
}